// Round 5
// baseline (563.170 us; speedup 1.0000x reference)
//
#include <hip/hip_runtime.h>
#include <cstdint>
#include <cstddef>

typedef __bf16 bf16_t;
typedef __attribute__((ext_vector_type(8))) __bf16 bf16x8;
typedef __attribute__((ext_vector_type(4))) __bf16 bf16x4;
typedef __attribute__((ext_vector_type(4))) float floatx4;

#define NB 32
#define NW 168
#define NM 2048
#define NHID 128
#define NBW (NB * NW)  // 5376
#define GEMM_BLOCKS 672  // (NBW/128) * (NM/128)

#define GLOAD_LDS16(g, l)                                          \
  __builtin_amdgcn_global_load_lds(                                \
      (const __attribute__((address_space(1))) void*)(g),          \
      (__attribute__((address_space(3))) void*)(l), 16, 0, 0)

// One-shot prep: blocks [0,2688): x -> Xb [(b,w)][m] bf16 + XT [m][(b,w)] bf16;
// [2688,3200): L -> Lb bf16; [3200,3207): W1 -> W1p [7][128][192] bf16, k>=168 zeroed.
__global__ void prep_all(const float* __restrict__ x, bf16_t* __restrict__ Xb,
                         bf16_t* __restrict__ XT, const float* __restrict__ L,
                         bf16_t* __restrict__ Lb, const float* __restrict__ W1,
                         bf16_t* __restrict__ W1p) {
  __shared__ float tile[64][65];
  int bid = blockIdx.x;
  int t = threadIdx.x;
  if (bid < 2688) {
    const int C = NM;
    int r0 = (bid >> 5) * 64, c0 = (bid & 31) * 64;
    int tr = t >> 4, tc4 = (t & 15) * 4;
#pragma unroll
    for (int p = 0; p < 4; ++p) {
      int row = p * 16 + tr;
      float4 v = *(const float4*)(x + (size_t)(r0 + row) * C + c0 + tc4);
      tile[row][tc4 + 0] = v.x;
      tile[row][tc4 + 1] = v.y;
      tile[row][tc4 + 2] = v.z;
      tile[row][tc4 + 3] = v.w;
      bf16x4 o = {(bf16_t)v.x, (bf16_t)v.y, (bf16_t)v.z, (bf16_t)v.w};
      *(bf16x4*)(Xb + (size_t)(r0 + row) * C + c0 + tc4) = o;
    }
    __syncthreads();
#pragma unroll
    for (int p = 0; p < 4; ++p) {
      int c = p * 16 + tr;
      bf16x4 o = {(bf16_t)tile[tc4 + 0][c], (bf16_t)tile[tc4 + 1][c],
                  (bf16_t)tile[tc4 + 2][c], (bf16_t)tile[tc4 + 3][c]};
      *(bf16x4*)(XT + (size_t)(c0 + c) * NBW + r0 + tc4) = o;
    }
  } else if (bid < 3200) {
    int i = (bid - 2688) * 256 + t;
    const int n4 = NM * NM / 4;
    const int stride = 512 * 256;
    for (; i < n4; i += stride) {
      float4 v = ((const float4*)L)[i];
      bf16x4 o = {(bf16_t)v.x, (bf16_t)v.y, (bf16_t)v.z, (bf16_t)v.w};
      ((bf16x4*)Lb)[i] = o;
    }
  } else {
    int hop = bid - 3200;
    const float* src = W1 + (size_t)hop * NHID * NW;
    bf16_t* dst = W1p + (size_t)hop * NHID * 192;
    // chunks of 8: 128*24 = 3072 chunks; chunk c -> h=c/24, kc=c%24
    for (int c = t; c < 3072; c += 256) {
      int h = c / 24, kc = c % 24;
      bf16x8 o;
      if (kc < 21) {
        const float* s = src + (size_t)h * NW + kc * 8;
#pragma unroll
        for (int j = 0; j < 8; ++j) o[j] = (bf16_t)s[j];
      } else {
#pragma unroll
        for (int j = 0; j < 8; ++j) o[j] = (bf16_t)0.0f;
      }
      *(bf16x8*)(dst + (size_t)h * 192 + kc * 8) = o;
    }
  }
}

// Fused hop dispatch.
// Blocks [0, gemm_blocks): NT GEMM Tt_i = A * Lb^T  (m97 async-LDS structure),
//   writes Tt (row-major, if write_c) and XTout (transposed) for the next MLP.
// Blocks [gemm_blocks, +512): MLP for hop `hop` on XTin:
//   H = relu(XTin_row * W1p[hop]^T + b1); score = H . W2 + b2 -> out[b*NM+m].
//   B-fragments read from global W1p (L1/L2-resident, zero-padded to K=192).
__global__ void fused_hop(const bf16_t* __restrict__ A, const bf16_t* __restrict__ Lb,
                          bf16_t* __restrict__ Tt, bf16_t* __restrict__ XTout,
                          const bf16_t* __restrict__ XTin, const bf16_t* __restrict__ W1p,
                          const float* __restrict__ b1, const float* __restrict__ W2,
                          const float* __restrict__ b2, float* __restrict__ out,
                          int hop, int accumulate, int gemm_blocks, int write_c) {
  __shared__ bf16_t As[128 * 32];
  __shared__ bf16_t Bs[128 * 32];
  __shared__ float sred[4][64];
  int tid = threadIdx.x;
  int lane = tid & 63, wv = tid >> 6;
  int wm = wv >> 1, wn = wv & 1;
  int quad = lane >> 4, l15 = lane & 15;
  floatx4 zero4 = {0.f, 0.f, 0.f, 0.f};
  floatx4 acc[4][4];
#pragma unroll
  for (int mi = 0; mi < 4; ++mi)
#pragma unroll
    for (int ni = 0; ni < 4; ++ni) acc[mi][ni] = zero4;

  if ((int)blockIdx.x < gemm_blocks) {
    // ---------------- GEMM path ----------------
    int bid = blockIdx.x;
    int m0 = (bid >> 4) * 128, n0 = (bid & 15) * 128;
    // staging: wave wv handles chunks [wv*128, wv*128+128); global-side XOR swizzle
    int p0 = wv * 128 + lane;
    int p1 = p0 + 64;
    int row0 = p0 >> 2, kc0 = (p0 & 3) ^ ((p0 >> 3) & 3);
    int row1 = p1 >> 2, kc1 = (p1 & 3) ^ ((p1 >> 3) & 3);
    const bf16_t* a0p = A + (size_t)(m0 + row0) * NM + kc0 * 8;
    const bf16_t* a1p = A + (size_t)(m0 + row1) * NM + kc1 * 8;
    const bf16_t* b0p = Lb + (size_t)(n0 + row0) * NM + kc0 * 8;
    const bf16_t* b1p = Lb + (size_t)(n0 + row1) * NM + kc1 * 8;
    bf16_t* As_d0 = As + (size_t)(wv * 128) * 8;
    bf16_t* As_d1 = As + (size_t)(wv * 128 + 64) * 8;
    bf16_t* Bs_d0 = Bs + (size_t)(wv * 128) * 8;
    bf16_t* Bs_d1 = Bs + (size_t)(wv * 128 + 64) * 8;
    int swz = (l15 >> 1) & 3;
    int kpos = (quad ^ swz) * 8;

    for (int kb = 0; kb < 2048; kb += 32) {
      GLOAD_LDS16(a0p + kb, As_d0);
      GLOAD_LDS16(a1p + kb, As_d1);
      GLOAD_LDS16(b0p + kb, Bs_d0);
      GLOAD_LDS16(b1p + kb, Bs_d1);
      __syncthreads();
      bf16x8 af[4], bf[4];
#pragma unroll
      for (int mi = 0; mi < 4; ++mi)
        af[mi] = *(const bf16x8*)(As + (wm * 64 + mi * 16 + l15) * 32 + kpos);
#pragma unroll
      for (int ni = 0; ni < 4; ++ni)
        bf[ni] = *(const bf16x8*)(Bs + (wn * 64 + ni * 16 + l15) * 32 + kpos);
#pragma unroll
      for (int mi = 0; mi < 4; ++mi)
#pragma unroll
        for (int ni = 0; ni < 4; ++ni)
          acc[mi][ni] =
              __builtin_amdgcn_mfma_f32_16x16x32_bf16(af[mi], bf[ni], acc[mi][ni], 0, 0, 0);
      __syncthreads();
    }
#pragma unroll
    for (int mi = 0; mi < 4; ++mi) {
#pragma unroll
      for (int ni = 0; ni < 4; ++ni) {
        int col = n0 + wn * 64 + ni * 16 + l15;
        int rowb = m0 + wm * 64 + mi * 16 + quad * 4;
        bf16x4 tv;
#pragma unroll
        for (int r = 0; r < 4; ++r) tv[r] = (bf16_t)acc[mi][ni][r];
        *(bf16x4*)(XTout + (size_t)col * NBW + rowb) = tv;
        if (write_c) {
#pragma unroll
          for (int r = 0; r < 4; ++r) Tt[(size_t)(rowb + r) * NM + col] = tv[r];
        }
      }
    }
  } else {
    // ---------------- MLP path ----------------
    int bid2 = blockIdx.x - gemm_blocks;
    int r0 = bid2 * 128;  // rows r = m*32 + b
    const bf16_t* Wh = W1p + (size_t)hop * NHID * 192;
    const float* b1h = b1 + hop * NHID;
    const float* w2h = W2 + hop * NHID;
    // A row pointers: row R = r0 + wm*64 + mi*16 + l15; T row (m,b) at m*NBW + b*NW
    const bf16_t* arow[4];
#pragma unroll
    for (int mi = 0; mi < 4; ++mi) {
      int R = r0 + wm * 64 + mi * 16 + l15;
      arow[mi] = XTin + (size_t)(R >> 5) * NBW + (size_t)(R & 31) * NW + quad * 8;
    }
#pragma unroll
    for (int kb = 0; kb < 192; kb += 32) {
      int kc = (kb >> 3) + quad;  // 0..23
      bf16x8 af[4], bf[4];
#pragma unroll
      for (int mi = 0; mi < 4; ++mi)
        af[mi] = *(const bf16x8*)(arow[mi] + kb);  // k>=168 garbage; W1p pad=0
#pragma unroll
      for (int ni = 0; ni < 4; ++ni) {
        int h = wn * 64 + ni * 16 + l15;
        bf[ni] = *(const bf16x8*)(Wh + (size_t)h * 192 + kc * 8);
      }
#pragma unroll
      for (int mi = 0; mi < 4; ++mi)
#pragma unroll
        for (int ni = 0; ni < 4; ++ni)
          acc[mi][ni] =
              __builtin_amdgcn_mfma_f32_16x16x32_bf16(af[mi], bf[ni], acc[mi][ni], 0, 0, 0);
    }
    // epilogue: relu(H + b1) dot W2 per row
    float part[4][4];
#pragma unroll
    for (int mi = 0; mi < 4; ++mi)
#pragma unroll
      for (int r = 0; r < 4; ++r) part[mi][r] = 0.f;
#pragma unroll
    for (int ni = 0; ni < 4; ++ni) {
      int col = wn * 64 + ni * 16 + l15;
      float b1v = b1h[col];
      float w2v = w2h[col];
#pragma unroll
      for (int mi = 0; mi < 4; ++mi)
#pragma unroll
        for (int r = 0; r < 4; ++r) {
          float h = acc[mi][ni][r] + b1v;
          h = h > 0.f ? h : 0.f;
          part[mi][r] += h * w2v;
        }
    }
#pragma unroll
    for (int off = 1; off < 16; off <<= 1)
#pragma unroll
      for (int mi = 0; mi < 4; ++mi)
#pragma unroll
        for (int r = 0; r < 4; ++r) part[mi][r] += __shfl_xor(part[mi][r], off);
    if (l15 == 0) {
#pragma unroll
      for (int mi = 0; mi < 4; ++mi)
#pragma unroll
        for (int r = 0; r < 4; ++r) sred[wv][mi * 16 + quad * 4 + r] = part[mi][r];
    }
    __syncthreads();
    if (tid < 128) {
      int half = tid >> 6;
      int lr = tid & 63;
      float v = sred[half * 2][lr] + sred[half * 2 + 1][lr] + b2[hop];
      int R = r0 + half * 64 + lr;
      int idx = (R & 31) * NM + (R >> 5);  // out[b*M + m]
      if (accumulate)
        out[idx] += v;  // safe: block-exclusive rows within a dispatch, hops serialized
      else
        out[idx] = v;
    }
  }
}

extern "C" void kernel_launch(void* const* d_in, const int* in_sizes, int n_in,
                              void* d_out, int out_size, void* d_ws, size_t ws_size,
                              hipStream_t stream) {
  const float* x = (const float*)d_in[0];
  const float* L = (const float*)d_in[1];
  const float* W1 = (const float*)d_in[2];
  const float* b1 = (const float*)d_in[3];
  const float* W2 = (const float*)d_in[4];
  const float* b2 = (const float*)d_in[5];
  float* out = (float*)d_out;

  char* ws = (char*)d_ws;
  size_t off = 0;
  auto walloc = [&](size_t bytes) -> void* {
    off = (off + 255) & ~(size_t)255;
    void* p = ws + off;
    off += bytes;
    return p;
  };
  const size_t SZ_T = (size_t)NBW * NM * 2;  // 22 MB
  bf16_t* W1p = (bf16_t*)walloc((size_t)7 * NHID * 192 * 2);
  bf16_t* Lb = (bf16_t*)walloc((size_t)NM * NM * 2);
  bf16_t* Xb = (bf16_t*)walloc(SZ_T);
  bf16_t* Tta = (bf16_t*)walloc(SZ_T);
  bf16_t* Ttb = (bf16_t*)walloc(SZ_T);
  bf16_t* XTa = (bf16_t*)walloc(SZ_T);
  bf16_t* XTb = (bf16_t*)walloc(SZ_T);
  walloc(4096);  // guard: MLP A-pad reads overrun rows by <=48B
  (void)ws_size; (void)in_sizes; (void)n_in; (void)out_size;

  prep_all<<<dim3(3207), dim3(256), 0, stream>>>(x, Xb, XTa, L, Lb, W1, W1p);

  // D1..D6: GEMM hop i (T_i = T_{i-1} L^T, T_0 = X) || MLP hop i-1.
  // XTout alternates b,a,b,a,b,a; MLP reads the other one.
  fused_hop<<<dim3(GEMM_BLOCKS + 512), dim3(256), 0, stream>>>(
      Xb, Lb, Tta, XTb, XTa, W1p, b1, W2, b2, out, 0, 0, GEMM_BLOCKS, 1);
  fused_hop<<<dim3(GEMM_BLOCKS + 512), dim3(256), 0, stream>>>(
      Tta, Lb, Ttb, XTa, XTb, W1p, b1, W2, b2, out, 1, 1, GEMM_BLOCKS, 1);
  fused_hop<<<dim3(GEMM_BLOCKS + 512), dim3(256), 0, stream>>>(
      Ttb, Lb, Tta, XTb, XTa, W1p, b1, W2, b2, out, 2, 1, GEMM_BLOCKS, 1);
  fused_hop<<<dim3(GEMM_BLOCKS + 512), dim3(256), 0, stream>>>(
      Tta, Lb, Ttb, XTa, XTb, W1p, b1, W2, b2, out, 3, 1, GEMM_BLOCKS, 1);
  fused_hop<<<dim3(GEMM_BLOCKS + 512), dim3(256), 0, stream>>>(
      Ttb, Lb, Tta, XTb, XTa, W1p, b1, W2, b2, out, 4, 1, GEMM_BLOCKS, 1);
  fused_hop<<<dim3(GEMM_BLOCKS + 512), dim3(256), 0, stream>>>(
      Tta, Lb, Ttb, XTa, XTb, W1p, b1, W2, b2, out, 5, 1, GEMM_BLOCKS, 0);
  // D7: MLP only, hop 6 on XTa
  fused_hop<<<dim3(512), dim3(256), 0, stream>>>(
      Ttb, Lb, Tta, XTb, XTa, W1p, b1, W2, b2, out, 6, 1, 0, 0);
}